// Round 18
// baseline (437.958 us; speedup 1.0000x reference)
//
#include <hip/hip_runtime.h>
#include <hip/hip_bf16.h>

#define BB    4
#define CIN   64
#define COUT  128
#define HH    512
#define WW    512
#define BSZ   32
#define NBLK  512
#define NCELL 1024

typedef unsigned short u16;
typedef unsigned int   u32;
typedef __attribute__((ext_vector_type(8))) short bf8_t;    // 8 bf16 (4 VGPRs)
typedef __attribute__((ext_vector_type(4))) float f32x4;
typedef __attribute__((ext_vector_type(16))) float f32x16;

#define MFMA(a, b, c)   __builtin_amdgcn_mfma_f32_16x16x32_bf16((a), (b), (c), 0, 0, 0)
#define MFMA32(a, b, c) __builtin_amdgcn_mfma_f32_32x32x16_bf16((a), (b), (c), 0, 0, 0)

// swizzled byte offset inside a row-tile; px-major, channel-contiguous
// stride-256B rows (t1 / t2: 128 ch * 2B); (px&15)<<4 stays within the 256B row
#define SWZ256(px, k2) (((((px) << 8) + ((k2) << 1))) ^ (((px) & 15) << 4))
// stride-128B rows (xs: 64 ch * 2B)
#define SWZ128(px, k2) (((((px) << 7) + ((k2) << 1))) ^ (((px) & 7) << 4))

__device__ __forceinline__ u16 f2bf(float f) {
    u32 x = __float_as_uint(f);
    u32 r = x + 0x7fffu + ((x >> 16) & 1u);   // RNE
    return (u16)(r >> 16);
}
__device__ __forceinline__ uint2 pack4(float a, float b, float c, float d) {
    return make_uint2((u32)f2bf(a) | ((u32)f2bf(b) << 16),
                      (u32)f2bf(c) | ((u32)f2bf(d) << 16));
}

// ---- workspace layout (bytes) ----
// map   int[1024]                      @ 0
// biasf float[4][128]                  @ 4096  (b1,b2,b3,bd folded)
// w1f   u16[8][2][64][8]               @ 8192   16x16-frag order (g, ks32, lane, j)
// wdf   u16[8][2][64][8]               @ 24576  16x16-frag order
// w3f   u16[8][4][64][8]               @ 40960  16x16-frag order
// w2f   u16[9][4][8][64][8]            @ 73728  32x32-frag order (tap, q, ks16, lane, j)
// All weight loads are base + lane*16B -> one contiguous 1KB wave read.

__global__ void k_prep(const float* __restrict__ w1, const float* __restrict__ b1,
                       const float* __restrict__ w2, const float* __restrict__ b2,
                       const float* __restrict__ w3, const float* __restrict__ b3,
                       const float* __restrict__ wd, const float* __restrict__ bd,
                       const float* __restrict__ g1, const float* __restrict__ be1,
                       const float* __restrict__ m1, const float* __restrict__ v1,
                       const float* __restrict__ g2, const float* __restrict__ be2,
                       const float* __restrict__ m2, const float* __restrict__ v2,
                       const float* __restrict__ g3, const float* __restrict__ be3,
                       const float* __restrict__ m3, const float* __restrict__ v3,
                       void* wsv)
{
    int idx = blockIdx.x * 256 + threadIdx.x;
    int*   map   = (int*)wsv;
    float* biasf = (float*)((char*)wsv + 4096);
    u16*   w1f   = (u16*)((char*)wsv + 8192);
    u16*   wdf   = (u16*)((char*)wsv + 24576);
    u16*   w3f   = (u16*)((char*)wsv + 40960);
    u16*   w2f   = (u16*)((char*)wsv + 73728);

    if (idx < NCELL) map[idx] = -1;
    if (idx < 128) {
        float s1 = g1[idx] * rsqrtf(v1[idx] + 1e-5f);
        biasf[idx]       = (b1[idx] - m1[idx]) * s1 + be1[idx];
        float s2 = g2[idx] * rsqrtf(v2[idx] + 1e-5f);
        biasf[128 + idx] = (b2[idx] - m2[idx]) * s2 + be2[idx];
        float s3 = g3[idx] * rsqrtf(v3[idx] + 1e-5f);
        biasf[256 + idx] = (b3[idx] - m3[idx]) * s3 + be3[idx];
        biasf[384 + idx] = bd[idx];
    }
    if (idx < 8192) {   // w1f + wdf
        int g = idx >> 10, ks = (idx >> 9) & 1, lane = (idx >> 3) & 63, j = idx & 7;
        int cout = g * 16 + (lane & 15);
        int cin  = ks * 32 + (lane >> 4) * 8 + j;
        float s = g1[cout] * rsqrtf(v1[cout] + 1e-5f);
        w1f[idx] = f2bf(w1[cout * 64 + cin] * s);
        wdf[idx] = f2bf(wd[cout * 64 + cin]);
    }
    if (idx < 16384) {  // w3f
        int g = idx >> 11, ks = (idx >> 9) & 3, lane = (idx >> 3) & 63, j = idx & 7;
        int cout = g * 16 + (lane & 15);
        int cin  = ks * 32 + (lane >> 4) * 8 + j;
        float s = g3[cout] * rsqrtf(v3[cout] + 1e-5f);
        w3f[idx] = f2bf(w3[cout * 128 + cin] * s);
    }
    if (idx < 147456) { // w2f
        int tap = idx / 16384, q = (idx >> 12) & 3, ks = (idx >> 9) & 7;
        int lane = (idx >> 3) & 63, j = idx & 7;
        int cout = q * 32 + (lane & 31);
        int cin  = ks * 16 + (lane >> 5) * 8 + j;
        float s = g2[cout] * rsqrtf(v2[cout] + 1e-5f);
        w2f[idx] = f2bf(w2[(cout * 128 + cin) * 9 + tap] * s);
    }
}

__global__ void k_map(const int* __restrict__ ind, int* __restrict__ map)
{
    int i = threadIdx.x;  // 512
    int f = ind[i * 3] * 256 + ind[i * 3 + 1] * 16 + ind[i * 3 + 2];
    map[f] = 1;
}

// One 512-thread workgroup (8 waves) per active block; MFMA pipeline.
// Two phases per 4-row iteration; all swizzled LDS offsets hoisted to
// per-lane constants. (= round-17 best, unchanged)
__global__ __launch_bounds__(512, 2)
void k_main(const float* __restrict__ x, const int* __restrict__ ind,
            const void* __restrict__ wsv, float* __restrict__ out)
{
    __shared__ __align__(16) u16 t1s[8][34 * 128];   // 69632 B (halo'd, swizzled)
    __shared__ __align__(16) u16 t2ss[4][32 * 128];  // 32768 B
    __shared__ __align__(16) u16 xss[14][32 * 64];   // 57344 B
    __shared__ __align__(16) float bias_s[512];      //  2048 B
                                                     // total 161792 B <= 163840

    const float* biasf = (const float*)((const char*)wsv + 4096);
    const u16*   w1f   = (const u16*)((const char*)wsv + 8192);
    const u16*   wdf   = (const u16*)((const char*)wsv + 24576);
    const u16*   w3f   = (const u16*)((const char*)wsv + 40960);
    const u16*   w2f   = (const u16*)((const char*)wsv + 73728);

    const int blk = blockIdx.x;
    const int bi = ind[blk * 3 + 0];
    const int gy = ind[blk * 3 + 1];
    const int gx = ind[blk * 3 + 2];

    const int tid  = threadIdx.x;
    const int lane = tid & 63;
    const int wid  = tid >> 6;        // 0..7
    const int lcol = lane & 15;       // 16x16 MFMA col / A-row index
    const int lrow = lane >> 4;       // 0..3
    const int px32 = lane & 31;       // 32x32 MFMA col (px)
    const int hi   = lane >> 5;       // 32x32 k-half selector
    const int h    = wid & 1;         // row-half: rows 4p+2h, 4p+2h+1
    const int qh   = wid >> 1;        // cout quarter index (0..3)
    const int cb   = qh * 32;         // cout quarter base

    const size_t HW = (size_t)HH * WW;
    const float* xb = x   + (size_t)bi * CIN  * HW + (size_t)(gy * BSZ) * WW + (size_t)(gx * BSZ);
    float*       op = out + (size_t)bi * COUT * HW + (size_t)(gy * BSZ) * WW + (size_t)(gx * BSZ);

    const f32x4  zero4  = {0.f, 0.f, 0.f, 0.f};
    const f32x16 zero16 = {0,0,0,0, 0,0,0,0, 0,0,0,0, 0,0,0,0};

    auto m14 = [](int v) { return v >= 14 ? v - 14 : v; };

    // stage x rows r0 -> xss[sA], r0+1 -> xss[sB] (per-row bounds guards)
    auto stage2 = [&](int r0, int sA, int sB) {
        const int px = tid & 31, chq = (tid >> 5) & 15;   // 512 = 32 px * 16 ch-quads
        if (r0 < 32) {
            const float* sp0 = xb + (size_t)(chq * 4) * HW + (size_t)r0 * WW + px;
            float a0 = sp0[0], a1 = sp0[HW], a2 = sp0[2 * HW], a3 = sp0[3 * HW];
            *(uint2*)((char*)xss[sA] + SWZ128(px, chq * 4)) = pack4(a0, a1, a2, a3);
        }
        if (r0 + 1 < 32) {
            const float* sp1 = xb + (size_t)(chq * 4) * HW + (size_t)(r0 + 1) * WW + px;
            float b0 = sp1[0], b1 = sp1[HW], b2 = sp1[2 * HW], b3 = sp1[3 * HW];
            *(uint2*)((char*)xss[sB] + SWZ128(px, chq * 4)) = pack4(b0, b1, b2, b3);
        }
    };

    // conv1 + bn1 + relu for one row -> t1s[r & 7] (bf16, halo'd, swizzled)
    auto conv1_row = [&](int r, int xslot) {
        if (r > 32) return;
        f32x4 acc0 = zero4, acc1 = zero4;
        if (r < 32) {
            const char* xrow = (const char*)xss[xslot];
#pragma unroll
            for (int ks = 0; ks < 2; ++ks) {
                const int kb = ks * 32 + lrow * 8;
                bf8_t a  = *(const bf8_t*)(w1f + ((wid * 2 + ks) << 9) + lane * 8);
                bf8_t b0 = *(const bf8_t*)(xrow + SWZ128(lcol, kb));
                bf8_t b1 = *(const bf8_t*)(xrow + SWZ128(lcol + 16, kb));
                acc0 = MFMA(a, b0, acc0);
                acc1 = MFMA(a, b1, acc1);
            }
        }
        char* trow = (char*)t1s[r & 7];
        const int ch = wid * 16 + lrow * 4;
        uint2 p0, p1;
        if (r < 32) {
            f32x4 bv = *(const f32x4*)&bias_s[ch];
            p0 = pack4(fmaxf(acc0[0] + bv[0], 0.f), fmaxf(acc0[1] + bv[1], 0.f),
                       fmaxf(acc0[2] + bv[2], 0.f), fmaxf(acc0[3] + bv[3], 0.f));
            p1 = pack4(fmaxf(acc1[0] + bv[0], 0.f), fmaxf(acc1[1] + bv[1], 0.f),
                       fmaxf(acc1[2] + bv[2], 0.f), fmaxf(acc1[3] + bv[3], 0.f));
        } else {
            p0 = make_uint2(0u, 0u); p1 = p0;
        }
        *(uint2*)(trow + SWZ256(lcol + 1, ch))  = p0;
        *(uint2*)(trow + SWZ256(lcol + 17, ch)) = p1;
    };

    // ---- prologue ----
    for (int i = tid; i < 17408; i += 512) ((u32*)t1s)[i] = 0u;   // zero t1 ring (halos + row -1)
    bias_s[tid] = biasf[tid];
    stage2(0, 0, 1);
    stage2(2, 2, 3);
    stage2(4, 4, 5);
    stage2(6, 6, 7);
    stage2(8, 8, 9);
    __syncthreads();
    conv1_row(0, 0);
    conv1_row(1, 1);
    conv1_row(2, 2);
    conv1_row(3, 3);
    conv1_row(4, 4);
    __syncthreads();

    int s14 = 0;   // (4p) mod 14
    for (int p = 0; p < 8; ++p) {
        const int yA = 4 * p + 2 * h;      // wave's first output row

        // ---- phase A: conv2 (3x3, 32x32x16) + bn2 + relu -> t2 (2 rows per wave) ----
        {
            int off2[3][8];
#pragma unroll
            for (int tx = 0; tx < 3; ++tx)
#pragma unroll
                for (int ks = 0; ks < 8; ++ks)
                    off2[tx][ks] = SWZ256(px32 + tx, ks * 16 + hi * 8);

            f32x16 c2r0 = zero16, c2r1 = zero16;
            const u16* wtq = w2f + ((qh * 8) << 9);   // tap stride 16384
#pragma unroll 1
            for (int ty = 0; ty < 3; ++ty) {
                const char* tr0 = (const char*)t1s[(yA + ty - 1) & 7];
                const char* tr1 = (const char*)t1s[(yA + ty) & 7];
#pragma unroll
                for (int tx = 0; tx < 3; ++tx) {
                    const u16* wt = wtq + (ty * 3 + tx) * 16384;
#pragma unroll
                    for (int ks = 0; ks < 8; ++ks) {
                        bf8_t a  = *(const bf8_t*)(wt + (ks << 9) + lane * 8);
                        bf8_t b0 = *(const bf8_t*)(tr0 + off2[tx][ks]);
                        bf8_t b1 = *(const bf8_t*)(tr1 + off2[tx][ks]);
                        c2r0 = MFMA32(a, b0, c2r0);
                        c2r1 = MFMA32(a, b1, c2r1);
                    }
                }
            }
            // C layout 32x32: col = lane&31 (px), row = (reg&3) + 8*(reg>>2) + 4*hi
            char* t2row0 = (char*)t2ss[2 * h];
            char* t2row1 = (char*)t2ss[2 * h + 1];
#pragma unroll
            for (int q = 0; q < 4; ++q) {
                const int ch = cb + q * 8 + hi * 4;
                f32x4 bv = *(const f32x4*)&bias_s[128 + ch];
                uint2 pk0 = pack4(fmaxf(c2r0[4 * q + 0] + bv[0], 0.f),
                                  fmaxf(c2r0[4 * q + 1] + bv[1], 0.f),
                                  fmaxf(c2r0[4 * q + 2] + bv[2], 0.f),
                                  fmaxf(c2r0[4 * q + 3] + bv[3], 0.f));
                uint2 pk1 = pack4(fmaxf(c2r1[4 * q + 0] + bv[0], 0.f),
                                  fmaxf(c2r1[4 * q + 1] + bv[1], 0.f),
                                  fmaxf(c2r1[4 * q + 2] + bv[2], 0.f),
                                  fmaxf(c2r1[4 * q + 3] + bv[3], 0.f));
                *(uint2*)(t2row0 + SWZ256(px32, ch)) = pk0;
                *(uint2*)(t2row1 + SWZ256(px32, ch)) = pk1;
            }
        }
        __syncthreads();

        // ---- phase B: ds + conv3 + combine + store; conv1 rows 4p+5..4p+8;
        //      stage x rows 4p+10..4p+13 ----
        {
            bf8_t ad00 = *(const bf8_t*)(wdf + (((qh * 2 + 0) * 2 + 0) << 9) + lane * 8);
            bf8_t ad01 = *(const bf8_t*)(wdf + (((qh * 2 + 0) * 2 + 1) << 9) + lane * 8);
            bf8_t ad10 = *(const bf8_t*)(wdf + (((qh * 2 + 1) * 2 + 0) << 9) + lane * 8);
            bf8_t ad11 = *(const bf8_t*)(wdf + (((qh * 2 + 1) * 2 + 1) << 9) + lane * 8);
            bf8_t a300 = *(const bf8_t*)(w3f + (((qh * 2 + 0) * 4 + 0) << 9) + lane * 8);
            bf8_t a301 = *(const bf8_t*)(w3f + (((qh * 2 + 0) * 4 + 1) << 9) + lane * 8);
            bf8_t a302 = *(const bf8_t*)(w3f + (((qh * 2 + 0) * 4 + 2) << 9) + lane * 8);
            bf8_t a303 = *(const bf8_t*)(w3f + (((qh * 2 + 0) * 4 + 3) << 9) + lane * 8);
            bf8_t a310 = *(const bf8_t*)(w3f + (((qh * 2 + 1) * 4 + 0) << 9) + lane * 8);
            bf8_t a311 = *(const bf8_t*)(w3f + (((qh * 2 + 1) * 4 + 1) << 9) + lane * 8);
            bf8_t a312 = *(const bf8_t*)(w3f + (((qh * 2 + 1) * 4 + 2) << 9) + lane * 8);
            bf8_t a313 = *(const bf8_t*)(w3f + (((qh * 2 + 1) * 4 + 3) << 9) + lane * 8);

            int oxd[2][2], ot3[2][2], ot3b[2][2];
#pragma unroll
            for (int ks = 0; ks < 2; ++ks) {
                oxd[ks][0] = SWZ128(lcol, ks * 32 + lrow * 8);
                oxd[ks][1] = SWZ128(lcol + 16, ks * 32 + lrow * 8);
                ot3[ks][0] = SWZ256(lcol, ks * 32 + lrow * 8);
                ot3[ks][1] = SWZ256(lcol + 16, ks * 32 + lrow * 8);
                ot3b[ks][0] = SWZ256(lcol, (ks + 2) * 32 + lrow * 8);
                ot3b[ks][1] = SWZ256(lcol + 16, (ks + 2) * 32 + lrow * 8);
            }

            f32x4 cd[2][4];
#pragma unroll
            for (int m = 0; m < 2; ++m)
#pragma unroll
                for (int n = 0; n < 4; ++n) cd[m][n] = zero4;
            const char* xr0 = (const char*)xss[m14(s14 + 2 * h)];
            const char* xr1 = (const char*)xss[m14(s14 + 2 * h + 1)];
#pragma unroll
            for (int ks = 0; ks < 2; ++ks) {
                bf8_t a0  = ks ? ad01 : ad00;
                bf8_t a1  = ks ? ad11 : ad10;
                bf8_t b00 = *(const bf8_t*)(xr0 + oxd[ks][0]);
                bf8_t b01 = *(const bf8_t*)(xr0 + oxd[ks][1]);
                bf8_t b10 = *(const bf8_t*)(xr1 + oxd[ks][0]);
                bf8_t b11 = *(const bf8_t*)(xr1 + oxd[ks][1]);
                cd[0][0] = MFMA(a0, b00, cd[0][0]);  cd[0][1] = MFMA(a0, b01, cd[0][1]);
                cd[0][2] = MFMA(a0, b10, cd[0][2]);  cd[0][3] = MFMA(a0, b11, cd[0][3]);
                cd[1][0] = MFMA(a1, b00, cd[1][0]);  cd[1][1] = MFMA(a1, b01, cd[1][1]);
                cd[1][2] = MFMA(a1, b10, cd[1][2]);  cd[1][3] = MFMA(a1, b11, cd[1][3]);
            }
            f32x4 c3[2][4];
#pragma unroll
            for (int m = 0; m < 2; ++m)
#pragma unroll
                for (int n = 0; n < 4; ++n) c3[m][n] = zero4;
            const char* t20 = (const char*)t2ss[2 * h];
            const char* t21 = (const char*)t2ss[2 * h + 1];
#pragma unroll
            for (int ks = 0; ks < 4; ++ks) {
                bf8_t a0  = (ks == 0) ? a300 : (ks == 1) ? a301 : (ks == 2) ? a302 : a303;
                bf8_t a1  = (ks == 0) ? a310 : (ks == 1) ? a311 : (ks == 2) ? a312 : a313;
                const int k2 = ks & 1;
                const int o0 = (ks < 2) ? ot3[k2][0] : ot3b[k2][0];
                const int o1 = (ks < 2) ? ot3[k2][1] : ot3b[k2][1];
                bf8_t b00 = *(const bf8_t*)(t20 + o0);
                bf8_t b01 = *(const bf8_t*)(t20 + o1);
                bf8_t b10 = *(const bf8_t*)(t21 + o0);
                bf8_t b11 = *(const bf8_t*)(t21 + o1);
                c3[0][0] = MFMA(a0, b00, c3[0][0]);  c3[0][1] = MFMA(a0, b01, c3[0][1]);
                c3[0][2] = MFMA(a0, b10, c3[0][2]);  c3[0][3] = MFMA(a0, b11, c3[0][3]);
                c3[1][0] = MFMA(a1, b00, c3[1][0]);  c3[1][1] = MFMA(a1, b01, c3[1][1]);
                c3[1][2] = MFMA(a1, b10, c3[1][2]);  c3[1][3] = MFMA(a1, b11, c3[1][3]);
            }
#pragma unroll
            for (int m = 0; m < 2; ++m) {
                const int ch = cb + m * 16 + lrow * 4;
                f32x4 bv3 = *(const f32x4*)&bias_s[256 + ch];
                f32x4 bvd = *(const f32x4*)&bias_s[384 + ch];
#pragma unroll
                for (int rh = 0; rh < 2; ++rh) {
                    const int y = yA + rh;
#pragma unroll
                    for (int nt = 0; nt < 2; ++nt) {
                        const int n = 2 * rh + nt;
#pragma unroll
                        for (int j = 0; j < 4; ++j) {
                            float val = fmaxf(c3[m][n][j] + bv3[j], 0.f) + cd[m][n][j] + bvd[j];
                            op[(size_t)(ch + j) * HW + (size_t)y * WW + nt * 16 + lcol] = val;
                        }
                    }
                }
            }
        }
        conv1_row(4 * p + 5, m14(s14 + 5));
        conv1_row(4 * p + 6, m14(s14 + 6));
        conv1_row(4 * p + 7, m14(s14 + 7));
        conv1_row(4 * p + 8, m14(s14 + 8));
        stage2(4 * p + 10, m14(s14 + 10), m14(s14 + 11));
        stage2(4 * p + 12, m14(s14 + 12), m14(s14 + 13));
        __syncthreads();

        s14 = m14(s14 + 4);
    }
}

// downsample-only for inactive cells (MFMA).
// 2048 blocks x 256 threads: block = (cell, row-half); 8 iterations x 2 rows.
// Small LDS (8.5 KB) + low VGPR -> many blocks/CU for BW saturation.
__global__ __launch_bounds__(256)
void k_inactive(const float* __restrict__ x, const void* __restrict__ wsv,
                float* __restrict__ out)
{
    const int* map = (const int*)wsv;
    const int cell = blockIdx.x >> 1;
    if (map[cell] > 0) return;
    const int half = blockIdx.x & 1;

    __shared__ __align__(16) u16 xs[2][32 * 64];   // 8192 B
    __shared__ __align__(16) float bds[128];

    const float* biasf = (const float*)((const char*)wsv + 4096);
    const u16*   wdf   = (const u16*)((const char*)wsv + 24576);

    int bi = cell >> 8;
    int gy = (cell >> 4) & 15;
    int gx = cell & 15;

    const int tid  = threadIdx.x;      // 0..255 (4 waves)
    const int lane = tid & 63;
    const int w    = tid >> 6;         // 0..3
    const int lcol = lane & 15;
    const int lrow = lane >> 4;
    const int mh   = w & 1;            // cout half (64)
    const int rr   = w >> 1;           // row in pair
    const int cb   = mh * 64;
    const int gb   = mh * 4;           // 16-cout group base for wdf

    const size_t HW = (size_t)HH * WW;
    const float* xb = x   + (size_t)bi * CIN  * HW + (size_t)(gy * BSZ) * WW + (size_t)(gx * BSZ);
    float*       op = out + (size_t)bi * COUT * HW + (size_t)(gy * BSZ) * WW + (size_t)(gx * BSZ);

    if (tid < 128) bds[tid] = biasf[384 + tid];

    const f32x4 zero4 = {0.f, 0.f, 0.f, 0.f};

    for (int it = 0; it < 8; ++it) {
        const int y0 = half * 16 + 2 * it;
        {
            const int px = tid & 31, cq = (tid >> 5) & 7;   // 256 = 32 px * 8 quads
#pragma unroll
            for (int r = 0; r < 2; ++r) {
#pragma unroll
                for (int hc = 0; hc < 2; ++hc) {
                    const int q = cq + hc * 8;              // 16 quads = 64 ch
                    const float* sp = xb + (size_t)(q * 4) * HW + (size_t)(y0 + r) * WW + px;
                    float v0 = sp[0], v1 = sp[HW], v2 = sp[2 * HW], v3 = sp[3 * HW];
                    *(uint2*)((char*)xs[r] + SWZ128(px, q * 4)) = pack4(v0, v1, v2, v3);
                }
            }
        }
        __syncthreads();

        f32x4 cd[4][2];
#pragma unroll
        for (int m = 0; m < 4; ++m) { cd[m][0] = zero4; cd[m][1] = zero4; }
        const char* xrow = (const char*)xs[rr];
#pragma unroll
        for (int ks = 0; ks < 2; ++ks) {
            const int kb = ks * 32 + lrow * 8;
            bf8_t a0 = *(const bf8_t*)(wdf + (((gb + 0) * 2 + ks) << 9) + lane * 8);
            bf8_t a1 = *(const bf8_t*)(wdf + (((gb + 1) * 2 + ks) << 9) + lane * 8);
            bf8_t a2 = *(const bf8_t*)(wdf + (((gb + 2) * 2 + ks) << 9) + lane * 8);
            bf8_t a3 = *(const bf8_t*)(wdf + (((gb + 3) * 2 + ks) << 9) + lane * 8);
            bf8_t b0 = *(const bf8_t*)(xrow + SWZ128(lcol, kb));
            bf8_t b1 = *(const bf8_t*)(xrow + SWZ128(lcol + 16, kb));
            cd[0][0] = MFMA(a0, b0, cd[0][0]);  cd[0][1] = MFMA(a0, b1, cd[0][1]);
            cd[1][0] = MFMA(a1, b0, cd[1][0]);  cd[1][1] = MFMA(a1, b1, cd[1][1]);
            cd[2][0] = MFMA(a2, b0, cd[2][0]);  cd[2][1] = MFMA(a2, b1, cd[2][1]);
            cd[3][0] = MFMA(a3, b0, cd[3][0]);  cd[3][1] = MFMA(a3, b1, cd[3][1]);
        }
        const int y = y0 + rr;
#pragma unroll
        for (int m = 0; m < 4; ++m) {
            const int ch = cb + m * 16 + lrow * 4;
            f32x4 bv = *(const f32x4*)&bds[ch];
#pragma unroll
            for (int nt = 0; nt < 2; ++nt) {
#pragma unroll
                for (int j = 0; j < 4; ++j) {
                    op[(size_t)(ch + j) * HW + (size_t)y * WW + nt * 16 + lcol] = cd[m][nt][j] + bv[j];
                }
            }
        }
        __syncthreads();
    }
}

extern "C" void kernel_launch(void* const* d_in, const int* in_sizes, int n_in,
                              void* d_out, int out_size, void* d_ws, size_t ws_size,
                              hipStream_t stream)
{
    const float* x   = (const float*)d_in[0];
    const int*   ind = (const int*)d_in[1];
    const float* w1  = (const float*)d_in[2];
    const float* b1  = (const float*)d_in[3];
    const float* w2  = (const float*)d_in[4];
    const float* b2  = (const float*)d_in[5];
    const float* w3  = (const float*)d_in[6];
    const float* b3  = (const float*)d_in[7];
    const float* wd  = (const float*)d_in[8];
    const float* bd  = (const float*)d_in[9];
    const float* g1  = (const float*)d_in[10];
    const float* be1 = (const float*)d_in[11];
    const float* m1  = (const float*)d_in[12];
    const float* v1  = (const float*)d_in[13];
    const float* g2  = (const float*)d_in[14];
    const float* be2 = (const float*)d_in[15];
    const float* m2  = (const float*)d_in[16];
    const float* v2  = (const float*)d_in[17];
    const float* g3  = (const float*)d_in[18];
    const float* be3 = (const float*)d_in[19];
    const float* m3  = (const float*)d_in[20];
    const float* v3  = (const float*)d_in[21];

    float* out = (float*)d_out;

    hipLaunchKernelGGL(k_prep, dim3(576), dim3(256), 0, stream,
                       w1, b1, w2, b2, w3, b3, wd, bd,
                       g1, be1, m1, v1, g2, be2, m2, v2, g3, be3, m3, v3, d_ws);
    hipLaunchKernelGGL(k_map, dim3(1), dim3(NBLK), 0, stream, ind, (int*)d_ws);
    hipLaunchKernelGGL(k_main, dim3(NBLK), dim3(512), 0, stream, x, ind, d_ws, out);
    hipLaunchKernelGGL(k_inactive, dim3(2 * NCELL), dim3(256), 0, stream, x, d_ws, out);
}

// Round 19
// 404.297 us; speedup vs baseline: 1.0833x; 1.0833x over previous
//
#include <hip/hip_runtime.h>
#include <hip/hip_bf16.h>

#define BB    4
#define CIN   64
#define COUT  128
#define HH    512
#define WW    512
#define BSZ   32
#define NBLK  512
#define NCELL 1024

typedef unsigned short u16;
typedef unsigned int   u32;
typedef __attribute__((ext_vector_type(8))) short bf8_t;    // 8 bf16 (4 VGPRs)
typedef __attribute__((ext_vector_type(4))) float f32x4;
typedef __attribute__((ext_vector_type(16))) float f32x16;

#define MFMA(a, b, c)   __builtin_amdgcn_mfma_f32_16x16x32_bf16((a), (b), (c), 0, 0, 0)
#define MFMA32(a, b, c) __builtin_amdgcn_mfma_f32_32x32x16_bf16((a), (b), (c), 0, 0, 0)

// swizzled byte offset inside a row-tile; px-major, channel-contiguous
// stride-256B rows (t1 / t2: 128 ch * 2B); (px&15)<<4 stays within the 256B row
#define SWZ256(px, k2) (((((px) << 8) + ((k2) << 1))) ^ (((px) & 15) << 4))
// stride-128B rows (xs: 64 ch * 2B)
#define SWZ128(px, k2) (((((px) << 7) + ((k2) << 1))) ^ (((px) & 7) << 4))

__device__ __forceinline__ u16 f2bf(float f) {
    u32 x = __float_as_uint(f);
    u32 r = x + 0x7fffu + ((x >> 16) & 1u);   // RNE
    return (u16)(r >> 16);
}
__device__ __forceinline__ uint2 pack4(float a, float b, float c, float d) {
    return make_uint2((u32)f2bf(a) | ((u32)f2bf(b) << 16),
                      (u32)f2bf(c) | ((u32)f2bf(d) << 16));
}

// ---- workspace layout (bytes) ----
// map   int[1024]                      @ 0
// biasf float[4][128]                  @ 4096  (b1,b2,b3,bd folded)
// w1f   u16[8][2][64][8]               @ 8192   16x16-frag order (g, ks32, lane, j)
// wdf   u16[8][2][64][8]               @ 24576  16x16-frag order
// w3f   u16[8][4][64][8]               @ 40960  16x16-frag order
// w2f   u16[9][4][8][64][8]            @ 73728  32x32-frag order (tap, q, ks16, lane, j)
// list  int[1024]                      @ 368640 (compacted inactive cells)
// count int                            @ 372736

__global__ void k_prep(const float* __restrict__ w1, const float* __restrict__ b1,
                       const float* __restrict__ w2, const float* __restrict__ b2,
                       const float* __restrict__ w3, const float* __restrict__ b3,
                       const float* __restrict__ wd, const float* __restrict__ bd,
                       const float* __restrict__ g1, const float* __restrict__ be1,
                       const float* __restrict__ m1, const float* __restrict__ v1,
                       const float* __restrict__ g2, const float* __restrict__ be2,
                       const float* __restrict__ m2, const float* __restrict__ v2,
                       const float* __restrict__ g3, const float* __restrict__ be3,
                       const float* __restrict__ m3, const float* __restrict__ v3,
                       void* wsv)
{
    int idx = blockIdx.x * 256 + threadIdx.x;
    int*   map   = (int*)wsv;
    float* biasf = (float*)((char*)wsv + 4096);
    u16*   w1f   = (u16*)((char*)wsv + 8192);
    u16*   wdf   = (u16*)((char*)wsv + 24576);
    u16*   w3f   = (u16*)((char*)wsv + 40960);
    u16*   w2f   = (u16*)((char*)wsv + 73728);

    if (idx < NCELL) map[idx] = -1;
    if (idx < 128) {
        float s1 = g1[idx] * rsqrtf(v1[idx] + 1e-5f);
        biasf[idx]       = (b1[idx] - m1[idx]) * s1 + be1[idx];
        float s2 = g2[idx] * rsqrtf(v2[idx] + 1e-5f);
        biasf[128 + idx] = (b2[idx] - m2[idx]) * s2 + be2[idx];
        float s3 = g3[idx] * rsqrtf(v3[idx] + 1e-5f);
        biasf[256 + idx] = (b3[idx] - m3[idx]) * s3 + be3[idx];
        biasf[384 + idx] = bd[idx];
    }
    if (idx < 8192) {   // w1f + wdf
        int g = idx >> 10, ks = (idx >> 9) & 1, lane = (idx >> 3) & 63, j = idx & 7;
        int cout = g * 16 + (lane & 15);
        int cin  = ks * 32 + (lane >> 4) * 8 + j;
        float s = g1[cout] * rsqrtf(v1[cout] + 1e-5f);
        w1f[idx] = f2bf(w1[cout * 64 + cin] * s);
        wdf[idx] = f2bf(wd[cout * 64 + cin]);
    }
    if (idx < 16384) {  // w3f
        int g = idx >> 11, ks = (idx >> 9) & 3, lane = (idx >> 3) & 63, j = idx & 7;
        int cout = g * 16 + (lane & 15);
        int cin  = ks * 32 + (lane >> 4) * 8 + j;
        float s = g3[cout] * rsqrtf(v3[cout] + 1e-5f);
        w3f[idx] = f2bf(w3[cout * 128 + cin] * s);
    }
    if (idx < 147456) { // w2f
        int tap = idx / 16384, q = (idx >> 12) & 3, ks = (idx >> 9) & 7;
        int lane = (idx >> 3) & 63, j = idx & 7;
        int cout = q * 32 + (lane & 31);
        int cin  = ks * 16 + (lane >> 5) * 8 + j;
        float s = g2[cout] * rsqrtf(v2[cout] + 1e-5f);
        w2f[idx] = f2bf(w2[(cout * 128 + cin) * 9 + tap] * s);
    }
}

// single 1024-thread workgroup: mark active cells, then compact inactive list
__global__ void k_map(const int* __restrict__ ind, void* wsv)
{
    int*   map   = (int*)wsv;
    int*   list  = (int*)((char*)wsv + 368640);
    int*   count = (int*)((char*)wsv + 372736);

    int i = threadIdx.x;  // 0..1023
    if (i == 0) *count = 0;
    if (i < NBLK) {
        int f = ind[i * 3] * 256 + ind[i * 3 + 1] * 16 + ind[i * 3 + 2];
        map[f] = 1;
    }
    __syncthreads();
    if (map[i] < 0) {
        int pos = atomicAdd(count, 1);
        list[pos] = i;
    }
}

// One 512-thread workgroup (8 waves) per active block; MFMA pipeline.
// Two phases per 4-row iteration; all swizzled LDS offsets hoisted to
// per-lane constants. (= round-17 best, unchanged)
__global__ __launch_bounds__(512, 2)
void k_main(const float* __restrict__ x, const int* __restrict__ ind,
            const void* __restrict__ wsv, float* __restrict__ out)
{
    __shared__ __align__(16) u16 t1s[8][34 * 128];   // 69632 B (halo'd, swizzled)
    __shared__ __align__(16) u16 t2ss[4][32 * 128];  // 32768 B
    __shared__ __align__(16) u16 xss[14][32 * 64];   // 57344 B
    __shared__ __align__(16) float bias_s[512];      //  2048 B
                                                     // total 161792 B <= 163840

    const float* biasf = (const float*)((const char*)wsv + 4096);
    const u16*   w1f   = (const u16*)((const char*)wsv + 8192);
    const u16*   wdf   = (const u16*)((const char*)wsv + 24576);
    const u16*   w3f   = (const u16*)((const char*)wsv + 40960);
    const u16*   w2f   = (const u16*)((const char*)wsv + 73728);

    const int blk = blockIdx.x;
    const int bi = ind[blk * 3 + 0];
    const int gy = ind[blk * 3 + 1];
    const int gx = ind[blk * 3 + 2];

    const int tid  = threadIdx.x;
    const int lane = tid & 63;
    const int wid  = tid >> 6;        // 0..7
    const int lcol = lane & 15;       // 16x16 MFMA col / A-row index
    const int lrow = lane >> 4;       // 0..3
    const int px32 = lane & 31;       // 32x32 MFMA col (px)
    const int hi   = lane >> 5;       // 32x32 k-half selector
    const int h    = wid & 1;         // row-half: rows 4p+2h, 4p+2h+1
    const int qh   = wid >> 1;        // cout quarter index (0..3)
    const int cb   = qh * 32;         // cout quarter base

    const size_t HW = (size_t)HH * WW;
    const float* xb = x   + (size_t)bi * CIN  * HW + (size_t)(gy * BSZ) * WW + (size_t)(gx * BSZ);
    float*       op = out + (size_t)bi * COUT * HW + (size_t)(gy * BSZ) * WW + (size_t)(gx * BSZ);

    const f32x4  zero4  = {0.f, 0.f, 0.f, 0.f};
    const f32x16 zero16 = {0,0,0,0, 0,0,0,0, 0,0,0,0, 0,0,0,0};

    auto m14 = [](int v) { return v >= 14 ? v - 14 : v; };

    // stage x rows r0 -> xss[sA], r0+1 -> xss[sB] (per-row bounds guards)
    auto stage2 = [&](int r0, int sA, int sB) {
        const int px = tid & 31, chq = (tid >> 5) & 15;   // 512 = 32 px * 16 ch-quads
        if (r0 < 32) {
            const float* sp0 = xb + (size_t)(chq * 4) * HW + (size_t)r0 * WW + px;
            float a0 = sp0[0], a1 = sp0[HW], a2 = sp0[2 * HW], a3 = sp0[3 * HW];
            *(uint2*)((char*)xss[sA] + SWZ128(px, chq * 4)) = pack4(a0, a1, a2, a3);
        }
        if (r0 + 1 < 32) {
            const float* sp1 = xb + (size_t)(chq * 4) * HW + (size_t)(r0 + 1) * WW + px;
            float b0 = sp1[0], b1 = sp1[HW], b2 = sp1[2 * HW], b3 = sp1[3 * HW];
            *(uint2*)((char*)xss[sB] + SWZ128(px, chq * 4)) = pack4(b0, b1, b2, b3);
        }
    };

    // conv1 + bn1 + relu for one row -> t1s[r & 7] (bf16, halo'd, swizzled)
    auto conv1_row = [&](int r, int xslot) {
        if (r > 32) return;
        f32x4 acc0 = zero4, acc1 = zero4;
        if (r < 32) {
            const char* xrow = (const char*)xss[xslot];
#pragma unroll
            for (int ks = 0; ks < 2; ++ks) {
                const int kb = ks * 32 + lrow * 8;
                bf8_t a  = *(const bf8_t*)(w1f + ((wid * 2 + ks) << 9) + lane * 8);
                bf8_t b0 = *(const bf8_t*)(xrow + SWZ128(lcol, kb));
                bf8_t b1 = *(const bf8_t*)(xrow + SWZ128(lcol + 16, kb));
                acc0 = MFMA(a, b0, acc0);
                acc1 = MFMA(a, b1, acc1);
            }
        }
        char* trow = (char*)t1s[r & 7];
        const int ch = wid * 16 + lrow * 4;
        uint2 p0, p1;
        if (r < 32) {
            f32x4 bv = *(const f32x4*)&bias_s[ch];
            p0 = pack4(fmaxf(acc0[0] + bv[0], 0.f), fmaxf(acc0[1] + bv[1], 0.f),
                       fmaxf(acc0[2] + bv[2], 0.f), fmaxf(acc0[3] + bv[3], 0.f));
            p1 = pack4(fmaxf(acc1[0] + bv[0], 0.f), fmaxf(acc1[1] + bv[1], 0.f),
                       fmaxf(acc1[2] + bv[2], 0.f), fmaxf(acc1[3] + bv[3], 0.f));
        } else {
            p0 = make_uint2(0u, 0u); p1 = p0;
        }
        *(uint2*)(trow + SWZ256(lcol + 1, ch))  = p0;
        *(uint2*)(trow + SWZ256(lcol + 17, ch)) = p1;
    };

    // ---- prologue ----
    for (int i = tid; i < 17408; i += 512) ((u32*)t1s)[i] = 0u;   // zero t1 ring (halos + row -1)
    bias_s[tid] = biasf[tid];
    stage2(0, 0, 1);
    stage2(2, 2, 3);
    stage2(4, 4, 5);
    stage2(6, 6, 7);
    stage2(8, 8, 9);
    __syncthreads();
    conv1_row(0, 0);
    conv1_row(1, 1);
    conv1_row(2, 2);
    conv1_row(3, 3);
    conv1_row(4, 4);
    __syncthreads();

    int s14 = 0;   // (4p) mod 14
    for (int p = 0; p < 8; ++p) {
        const int yA = 4 * p + 2 * h;      // wave's first output row

        // ---- phase A: conv2 (3x3, 32x32x16) + bn2 + relu -> t2 (2 rows per wave) ----
        {
            int off2[3][8];
#pragma unroll
            for (int tx = 0; tx < 3; ++tx)
#pragma unroll
                for (int ks = 0; ks < 8; ++ks)
                    off2[tx][ks] = SWZ256(px32 + tx, ks * 16 + hi * 8);

            f32x16 c2r0 = zero16, c2r1 = zero16;
            const u16* wtq = w2f + ((qh * 8) << 9);   // tap stride 16384
#pragma unroll 1
            for (int ty = 0; ty < 3; ++ty) {
                const char* tr0 = (const char*)t1s[(yA + ty - 1) & 7];
                const char* tr1 = (const char*)t1s[(yA + ty) & 7];
#pragma unroll
                for (int tx = 0; tx < 3; ++tx) {
                    const u16* wt = wtq + (ty * 3 + tx) * 16384;
#pragma unroll
                    for (int ks = 0; ks < 8; ++ks) {
                        bf8_t a  = *(const bf8_t*)(wt + (ks << 9) + lane * 8);
                        bf8_t b0 = *(const bf8_t*)(tr0 + off2[tx][ks]);
                        bf8_t b1 = *(const bf8_t*)(tr1 + off2[tx][ks]);
                        c2r0 = MFMA32(a, b0, c2r0);
                        c2r1 = MFMA32(a, b1, c2r1);
                    }
                }
            }
            // C layout 32x32: col = lane&31 (px), row = (reg&3) + 8*(reg>>2) + 4*hi
            char* t2row0 = (char*)t2ss[2 * h];
            char* t2row1 = (char*)t2ss[2 * h + 1];
#pragma unroll
            for (int q = 0; q < 4; ++q) {
                const int ch = cb + q * 8 + hi * 4;
                f32x4 bv = *(const f32x4*)&bias_s[128 + ch];
                uint2 pk0 = pack4(fmaxf(c2r0[4 * q + 0] + bv[0], 0.f),
                                  fmaxf(c2r0[4 * q + 1] + bv[1], 0.f),
                                  fmaxf(c2r0[4 * q + 2] + bv[2], 0.f),
                                  fmaxf(c2r0[4 * q + 3] + bv[3], 0.f));
                uint2 pk1 = pack4(fmaxf(c2r1[4 * q + 0] + bv[0], 0.f),
                                  fmaxf(c2r1[4 * q + 1] + bv[1], 0.f),
                                  fmaxf(c2r1[4 * q + 2] + bv[2], 0.f),
                                  fmaxf(c2r1[4 * q + 3] + bv[3], 0.f));
                *(uint2*)(t2row0 + SWZ256(px32, ch)) = pk0;
                *(uint2*)(t2row1 + SWZ256(px32, ch)) = pk1;
            }
        }
        __syncthreads();

        // ---- phase B: ds + conv3 + combine + store; conv1 rows 4p+5..4p+8;
        //      stage x rows 4p+10..4p+13 ----
        {
            bf8_t ad00 = *(const bf8_t*)(wdf + (((qh * 2 + 0) * 2 + 0) << 9) + lane * 8);
            bf8_t ad01 = *(const bf8_t*)(wdf + (((qh * 2 + 0) * 2 + 1) << 9) + lane * 8);
            bf8_t ad10 = *(const bf8_t*)(wdf + (((qh * 2 + 1) * 2 + 0) << 9) + lane * 8);
            bf8_t ad11 = *(const bf8_t*)(wdf + (((qh * 2 + 1) * 2 + 1) << 9) + lane * 8);
            bf8_t a300 = *(const bf8_t*)(w3f + (((qh * 2 + 0) * 4 + 0) << 9) + lane * 8);
            bf8_t a301 = *(const bf8_t*)(w3f + (((qh * 2 + 0) * 4 + 1) << 9) + lane * 8);
            bf8_t a302 = *(const bf8_t*)(w3f + (((qh * 2 + 0) * 4 + 2) << 9) + lane * 8);
            bf8_t a303 = *(const bf8_t*)(w3f + (((qh * 2 + 0) * 4 + 3) << 9) + lane * 8);
            bf8_t a310 = *(const bf8_t*)(w3f + (((qh * 2 + 1) * 4 + 0) << 9) + lane * 8);
            bf8_t a311 = *(const bf8_t*)(w3f + (((qh * 2 + 1) * 4 + 1) << 9) + lane * 8);
            bf8_t a312 = *(const bf8_t*)(w3f + (((qh * 2 + 1) * 4 + 2) << 9) + lane * 8);
            bf8_t a313 = *(const bf8_t*)(w3f + (((qh * 2 + 1) * 4 + 3) << 9) + lane * 8);

            int oxd[2][2], ot3[2][2], ot3b[2][2];
#pragma unroll
            for (int ks = 0; ks < 2; ++ks) {
                oxd[ks][0] = SWZ128(lcol, ks * 32 + lrow * 8);
                oxd[ks][1] = SWZ128(lcol + 16, ks * 32 + lrow * 8);
                ot3[ks][0] = SWZ256(lcol, ks * 32 + lrow * 8);
                ot3[ks][1] = SWZ256(lcol + 16, ks * 32 + lrow * 8);
                ot3b[ks][0] = SWZ256(lcol, (ks + 2) * 32 + lrow * 8);
                ot3b[ks][1] = SWZ256(lcol + 16, (ks + 2) * 32 + lrow * 8);
            }

            f32x4 cd[2][4];
#pragma unroll
            for (int m = 0; m < 2; ++m)
#pragma unroll
                for (int n = 0; n < 4; ++n) cd[m][n] = zero4;
            const char* xr0 = (const char*)xss[m14(s14 + 2 * h)];
            const char* xr1 = (const char*)xss[m14(s14 + 2 * h + 1)];
#pragma unroll
            for (int ks = 0; ks < 2; ++ks) {
                bf8_t a0  = ks ? ad01 : ad00;
                bf8_t a1  = ks ? ad11 : ad10;
                bf8_t b00 = *(const bf8_t*)(xr0 + oxd[ks][0]);
                bf8_t b01 = *(const bf8_t*)(xr0 + oxd[ks][1]);
                bf8_t b10 = *(const bf8_t*)(xr1 + oxd[ks][0]);
                bf8_t b11 = *(const bf8_t*)(xr1 + oxd[ks][1]);
                cd[0][0] = MFMA(a0, b00, cd[0][0]);  cd[0][1] = MFMA(a0, b01, cd[0][1]);
                cd[0][2] = MFMA(a0, b10, cd[0][2]);  cd[0][3] = MFMA(a0, b11, cd[0][3]);
                cd[1][0] = MFMA(a1, b00, cd[1][0]);  cd[1][1] = MFMA(a1, b01, cd[1][1]);
                cd[1][2] = MFMA(a1, b10, cd[1][2]);  cd[1][3] = MFMA(a1, b11, cd[1][3]);
            }
            f32x4 c3[2][4];
#pragma unroll
            for (int m = 0; m < 2; ++m)
#pragma unroll
                for (int n = 0; n < 4; ++n) c3[m][n] = zero4;
            const char* t20 = (const char*)t2ss[2 * h];
            const char* t21 = (const char*)t2ss[2 * h + 1];
#pragma unroll
            for (int ks = 0; ks < 4; ++ks) {
                bf8_t a0  = (ks == 0) ? a300 : (ks == 1) ? a301 : (ks == 2) ? a302 : a303;
                bf8_t a1  = (ks == 0) ? a310 : (ks == 1) ? a311 : (ks == 2) ? a312 : a313;
                const int k2 = ks & 1;
                const int o0 = (ks < 2) ? ot3[k2][0] : ot3b[k2][0];
                const int o1 = (ks < 2) ? ot3[k2][1] : ot3b[k2][1];
                bf8_t b00 = *(const bf8_t*)(t20 + o0);
                bf8_t b01 = *(const bf8_t*)(t20 + o1);
                bf8_t b10 = *(const bf8_t*)(t21 + o0);
                bf8_t b11 = *(const bf8_t*)(t21 + o1);
                c3[0][0] = MFMA(a0, b00, c3[0][0]);  c3[0][1] = MFMA(a0, b01, c3[0][1]);
                c3[0][2] = MFMA(a0, b10, c3[0][2]);  c3[0][3] = MFMA(a0, b11, c3[0][3]);
                c3[1][0] = MFMA(a1, b00, c3[1][0]);  c3[1][1] = MFMA(a1, b01, c3[1][1]);
                c3[1][2] = MFMA(a1, b10, c3[1][2]);  c3[1][3] = MFMA(a1, b11, c3[1][3]);
            }
#pragma unroll
            for (int m = 0; m < 2; ++m) {
                const int ch = cb + m * 16 + lrow * 4;
                f32x4 bv3 = *(const f32x4*)&bias_s[256 + ch];
                f32x4 bvd = *(const f32x4*)&bias_s[384 + ch];
#pragma unroll
                for (int rh = 0; rh < 2; ++rh) {
                    const int y = yA + rh;
#pragma unroll
                    for (int nt = 0; nt < 2; ++nt) {
                        const int n = 2 * rh + nt;
#pragma unroll
                        for (int j = 0; j < 4; ++j) {
                            float val = fmaxf(c3[m][n][j] + bv3[j], 0.f) + cd[m][n][j] + bvd[j];
                            op[(size_t)(ch + j) * HW + (size_t)y * WW + nt * 16 + lcol] = val;
                        }
                    }
                }
            }
        }
        conv1_row(4 * p + 5, m14(s14 + 5));
        conv1_row(4 * p + 6, m14(s14 + 6));
        conv1_row(4 * p + 7, m14(s14 + 7));
        conv1_row(4 * p + 8, m14(s14 + 8));
        stage2(4 * p + 10, m14(s14 + 10), m14(s14 + 11));
        stage2(4 * p + 12, m14(s14 + 12), m14(s14 + 13));
        __syncthreads();

        s14 = m14(s14 + 4);
    }
}

// downsample-only for inactive cells (MFMA); one 512-thread WG per listed
// cell (compacted list, no dead blocks / early exits).
__global__ __launch_bounds__(512)
void k_inactive(const float* __restrict__ x, const void* __restrict__ wsv,
                float* __restrict__ out)
{
    const int* list = (const int*)((const char*)wsv + 368640);
    const int cell = list[blockIdx.x];

    __shared__ __align__(16) u16 xs2b[4][32 * 64];  // 16 KB
    __shared__ __align__(16) float bds[128];

    const float* biasf = (const float*)((const char*)wsv + 4096);
    const u16*   wdf   = (const u16*)((const char*)wsv + 24576);

    int bi = cell >> 8;
    int gy = (cell >> 4) & 15;
    int gx = cell & 15;

    const int tid  = threadIdx.x;
    const int lane = tid & 63;
    const int wid  = tid >> 6;
    const int lcol = lane & 15;
    const int lrow = lane >> 4;
    const int cb   = (wid >> 2) * 64;
    const int gb   = (wid >> 2) * 4;   // 16-cout group base for wdf
    const int wr   = wid & 3;

    const size_t HW = (size_t)HH * WW;
    const float* xb = x   + (size_t)bi * CIN  * HW + (size_t)(gy * BSZ) * WW + (size_t)(gx * BSZ);
    float*       op = out + (size_t)bi * COUT * HW + (size_t)(gy * BSZ) * WW + (size_t)(gx * BSZ);

    if (tid < 128) bds[tid] = biasf[384 + tid];

    const f32x4 zero4 = {0.f, 0.f, 0.f, 0.f};

    for (int y0 = 0; y0 < 32; y0 += 4) {
        {
            const int px = tid & 31, chq = (tid >> 5) & 15;
#pragma unroll
            for (int j = 0; j < 4; ++j) {
                const float* sp = xb + (size_t)(chq * 4) * HW + (size_t)(y0 + j) * WW + px;
                float v0 = sp[0], v1 = sp[HW], v2 = sp[2 * HW], v3 = sp[3 * HW];
                *(uint2*)((char*)xs2b[j] + SWZ128(px, chq * 4)) = pack4(v0, v1, v2, v3);
            }
        }
        __syncthreads();

        f32x4 cd[4][2];
#pragma unroll
        for (int m = 0; m < 4; ++m) { cd[m][0] = zero4; cd[m][1] = zero4; }
        const char* xrow = (const char*)xs2b[wr];
#pragma unroll
        for (int ks = 0; ks < 2; ++ks) {
            const int kb = ks * 32 + lrow * 8;
            bf8_t a0 = *(const bf8_t*)(wdf + (((gb + 0) * 2 + ks) << 9) + lane * 8);
            bf8_t a1 = *(const bf8_t*)(wdf + (((gb + 1) * 2 + ks) << 9) + lane * 8);
            bf8_t a2 = *(const bf8_t*)(wdf + (((gb + 2) * 2 + ks) << 9) + lane * 8);
            bf8_t a3 = *(const bf8_t*)(wdf + (((gb + 3) * 2 + ks) << 9) + lane * 8);
            bf8_t b0 = *(const bf8_t*)(xrow + SWZ128(lcol, kb));
            bf8_t b1 = *(const bf8_t*)(xrow + SWZ128(lcol + 16, kb));
            cd[0][0] = MFMA(a0, b0, cd[0][0]);  cd[0][1] = MFMA(a0, b1, cd[0][1]);
            cd[1][0] = MFMA(a1, b0, cd[1][0]);  cd[1][1] = MFMA(a1, b1, cd[1][1]);
            cd[2][0] = MFMA(a2, b0, cd[2][0]);  cd[2][1] = MFMA(a2, b1, cd[2][1]);
            cd[3][0] = MFMA(a3, b0, cd[3][0]);  cd[3][1] = MFMA(a3, b1, cd[3][1]);
        }
        const int y = y0 + wr;
#pragma unroll
        for (int m = 0; m < 4; ++m) {
            const int ch = cb + m * 16 + lrow * 4;
            f32x4 bv = *(const f32x4*)&bds[ch];
#pragma unroll
            for (int nt = 0; nt < 2; ++nt) {
#pragma unroll
                for (int j = 0; j < 4; ++j) {
                    op[(size_t)(ch + j) * HW + (size_t)y * WW + nt * 16 + lcol] = cd[m][nt][j] + bv[j];
                }
            }
        }
        __syncthreads();
    }
}

extern "C" void kernel_launch(void* const* d_in, const int* in_sizes, int n_in,
                              void* d_out, int out_size, void* d_ws, size_t ws_size,
                              hipStream_t stream)
{
    const float* x   = (const float*)d_in[0];
    const int*   ind = (const int*)d_in[1];
    const float* w1  = (const float*)d_in[2];
    const float* b1  = (const float*)d_in[3];
    const float* w2  = (const float*)d_in[4];
    const float* b2  = (const float*)d_in[5];
    const float* w3  = (const float*)d_in[6];
    const float* b3  = (const float*)d_in[7];
    const float* wd  = (const float*)d_in[8];
    const float* bd  = (const float*)d_in[9];
    const float* g1  = (const float*)d_in[10];
    const float* be1 = (const float*)d_in[11];
    const float* m1  = (const float*)d_in[12];
    const float* v1  = (const float*)d_in[13];
    const float* g2  = (const float*)d_in[14];
    const float* be2 = (const float*)d_in[15];
    const float* m2  = (const float*)d_in[16];
    const float* v2  = (const float*)d_in[17];
    const float* g3  = (const float*)d_in[18];
    const float* be3 = (const float*)d_in[19];
    const float* m3  = (const float*)d_in[20];
    const float* v3  = (const float*)d_in[21];

    float* out = (float*)d_out;

    hipLaunchKernelGGL(k_prep, dim3(576), dim3(256), 0, stream,
                       w1, b1, w2, b2, w3, b3, wd, bd,
                       g1, be1, m1, v1, g2, be2, m2, v2, g3, be3, m3, v3, d_ws);
    hipLaunchKernelGGL(k_map, dim3(1), dim3(NCELL), 0, stream, ind, d_ws);
    hipLaunchKernelGGL(k_main, dim3(NBLK), dim3(512), 0, stream, x, ind, d_ws, out);
    hipLaunchKernelGGL(k_inactive, dim3(NBLK), dim3(512), 0, stream, x, d_ws, out);
}